// Round 6
// baseline (156.181 us; speedup 1.0000x reference)
//
#include <hip/hip_runtime.h>
#include <math.h>
#include <float.h>

typedef unsigned long long u64;
typedef unsigned u32;

#define NT 1024        // fallback block size
#define NW 16
#define NT1 256        // streaming block size
#define NT4 256        // k4 block size (4 waves)
#define EPT 8          // elements per thread in k4 (CAP/NT4)
#define SL 8           // slices per row (k1, k3)
#define NB 8192        // 13-bit value buckets
#define BSH 19         // key >> BSH = bucket
#define CAP 2048       // candidate capacity per row
#define TOPN 5
#define SCALE_D 17592186044416.0  // 2^44 fixed-point scale
#define NEG_BIG -3.0e38f          // finite stand-in for -inf on output

struct RowCtl { u32 kb; u32 cnt0; u32 pad[30]; };   // 128 B

__device__ __forceinline__ u32 key_of(float f){
  u32 u = __float_as_uint(f);
  return (u & 0x80000000u) ? ~u : (u | 0x80000000u);
}
__device__ __forceinline__ float key_to_float(u32 k){
  u32 u = (k & 0x80000000u) ? (k & 0x7FFFFFFFu) : ~k;
  return __uint_as_float(u);
}
__device__ __forceinline__ u64 quantMass(float l, float m){
  float ef = expf(l - m);                 // <= 1
  return (u64)((double)ef * SCALE_D + 0.5);
}

struct Top5 { float v[TOPN]; int ix[TOPN]; };
__device__ __forceinline__ void t5_init(Top5& t){
  for (int j=0;j<TOPN;j++){ t.v[j] = -INFINITY; t.ix[j] = 0x7FFFFFFF; }
}
__device__ __forceinline__ void t5_insert(Top5& t, float nv, int ni){
  for (int j=0;j<TOPN;j++){
    if (nv > t.v[j] || (nv == t.v[j] && ni < t.ix[j])){
      for (int s=TOPN-1;s>j;s--){ t.v[s]=t.v[s-1]; t.ix[s]=t.ix[s-1]; }
      t.v[j]=nv; t.ix[j]=ni;
      return;
    }
  }
}

// exclusive prefix sum (1024 threads) for fallback only
__device__ void scan_excl(u64* arr, int n, u64* wsum){
  const int tid = threadIdx.x, lane = tid & 63, w = tid >> 6;
  __syncthreads();
  const int chunk = (n + NT - 1) / NT;
  const int base = tid * chunk;
  u64 local = 0;
  for (int j=0;j<chunk;j++){ int i=base+j; if (i<n) local += arr[i]; }
  u64 inc = local;
  for (int off=1; off<64; off<<=1){
    u64 up = __shfl_up(inc, off, 64);
    if (lane >= off) inc += up;
  }
  if (lane == 63) wsum[w] = inc;
  __syncthreads();
  if (tid == 0){
    u64 acc = 0;
    for (int i=0;i<NW;i++){ u64 v = wsum[i]; wsum[i] = acc; acc += v; }
    arr[n] = acc;
  }
  __syncthreads();
  u64 run = wsum[w] + (inc - local);
  for (int j=0;j<chunk;j++){ int i=base+j; if (i<n){ u64 v=arr[i]; arr[i]=run; run += v; } }
  __syncthreads();
}

// ======================= pipeline kernels =======================

__global__ void k0_zero(u32* __restrict__ hist, u32* __restrict__ ctlw, int Bn){
  size_t n = (size_t)Bn * NB;
  size_t stride = (size_t)gridDim.x * blockDim.x;
  for (size_t i = (size_t)blockIdx.x*blockDim.x + threadIdx.x; i < n; i += stride) hist[i] = 0;
  size_t nc = (size_t)Bn * (sizeof(RowCtl)/4);
  for (size_t i = (size_t)blockIdx.x*blockDim.x + threadIdx.x; i < nc; i += stride) ctlw[i] = 0;
}

__global__ __launch_bounds__(NT1) void k1_hist(const float* __restrict__ L,
        const float* __restrict__ temp, u32* __restrict__ hist, int Bn, int Vn){
  __shared__ u32 lh[NB];
  const int b = blockIdx.y, s = blockIdx.x, tid = threadIdx.x;
  for (int j=tid;j<NB;j+=NT1) lh[j]=0;
  const float tr = temp[b]; const float tEff = (tr < 1e-5f) ? 1.0f : tr;
  const float* Lr = L + (size_t)b*Vn;
  const int chunk = (Vn + SL-1)/SL;
  const int i0 = s*chunk, i1 = min(i0+chunk, Vn);
  __syncthreads();
  const int nv = (i1 - i0) / 4;
  const float4* L4 = (const float4*)(Lr + i0);
  for (int v=tid; v<nv; v+=NT1){
    float4 x = L4[v];
    #pragma unroll
    for (int e=0;e<4;e++){
      float l = (&x.x)[e] / tEff;
      atomicAdd(&lh[key_of(l)>>BSH], 1u);
    }
  }
  for (int i=i0+nv*4+tid; i<i1; i+=NT1){
    float l = Lr[i]/tEff;
    atomicAdd(&lh[key_of(l)>>BSH], 1u);
  }
  __syncthreads();
  u32* Hr = hist + (size_t)b*NB;
  for (int j=tid;j<NB;j+=NT1){ u32 c = lh[j]; if (c) atomicAdd(&Hr[j], c); }
}

__global__ __launch_bounds__(NT) void k2_kb(const int* __restrict__ top_k,
        const u32* __restrict__ hist, RowCtl* __restrict__ ctl, int Bn, int Vn){
  __shared__ u32 sh[NB+1];
  __shared__ u32 wsum[NW];
  __shared__ int s_g;
  const int b = blockIdx.x, tid = threadIdx.x, lane = tid&63, w = tid>>6;
  const u32* Hr = hist + (size_t)b*NB;
  for (int j=tid;j<NB;j+=NT) sh[j] = Hr[j];
  __syncthreads();
  const int chunk = NB/NT;  // 8
  u32 local=0;
  for (int j=0;j<chunk;j++) local += sh[tid*chunk+j];
  u32 inc = local;
  for (int off=1;off<64;off<<=1){ u32 up=__shfl_up(inc,off,64); if (lane>=off) inc+=up; }
  if (lane==63) wsum[w]=inc;
  __syncthreads();
  if (tid==0){ u32 acc=0; for(int i=0;i<NW;i++){u32 v=wsum[i]; wsum[i]=acc; acc+=v;} sh[NB]=acc; }
  __syncthreads();
  u32 run = wsum[w] + (inc - local);
  for (int j=0;j<chunk;j++){ int i2=tid*chunk+j; u32 v=sh[i2]; sh[i2]=run; run+=v; }
  __syncthreads();
  int kk = top_k[b]; if (kk<1) kk=1; if (kk>Vn) kk=Vn;
  const u32 rank = (u32)(Vn - kk);
  for (int j=tid;j<NB;j+=NT) if (sh[j] <= rank && rank < sh[j+1]) s_g = j;
  __syncthreads();
  if (tid==0) ctl[b].kb = (u32)s_g;
}

__global__ __launch_bounds__(NT1) void k3_collect(const float* __restrict__ L,
        const float* __restrict__ temp, u64* __restrict__ cand, RowCtl* __restrict__ ctl,
        int Bn, int Vn){
  const int b = blockIdx.y, s = blockIdx.x, tid = threadIdx.x;
  const float tr = temp[b]; const float tEff = (tr<1e-5f)?1.0f:tr;
  const u32 kbMinKey = ctl[b].kb << BSH;
  const float* Lr = L + (size_t)b*Vn;
  u64* Cr = cand + (size_t)b*CAP;
  const int chunk = (Vn + SL-1)/SL;
  const int i0 = s*chunk, i1 = min(i0+chunk, Vn);
  const int nv = (i1 - i0) / 4;
  const float4* L4 = (const float4*)(Lr + i0);
  const int lane = tid & 63;
  for (int v=tid; v<nv; v+=NT1){
    float4 x = L4[v];
    #pragma unroll
    for (int e=0;e<4;e++){
      float l = (&x.x)[e] / tEff;
      u32 k = key_of(l);
      bool pred = (k >= kbMinKey);
      u64 mk = __ballot(pred);
      if (mk){
        int leader = __ffsll((long long)mk) - 1;
        u32 base = 0;
        if (lane == leader) base = atomicAdd(&ctl[b].cnt0, (u32)__popcll(mk));
        base = __shfl(base, leader, 64);
        if (pred){
          u32 p = base + (u32)__popcll(mk & ((1ull<<lane)-1ull));
          if (p < CAP) Cr[p] = ((u64)k<<32) | (u64)(u32)(i0 + v*4 + e);
        }
      }
    }
  }
  for (int i=i0+nv*4+tid; i<i1; i+=NT1){
    float l = Lr[i]/tEff;
    u32 k = key_of(l);
    if (k >= kbMinKey){
      u32 p = atomicAdd(&ctl[b].cnt0, 1u);
      if (p < CAP) Cr[p] = ((u64)k<<32) | (u64)(u32)i;
    }
  }
}

// k4: register-resident binary-descent selection. No LDS atomics, 1 barrier/bit.
__global__ __launch_bounds__(NT4) void k4_solve(const float* __restrict__ L,
        const float* __restrict__ temp, const int* __restrict__ top_k,
        const float* __restrict__ top_p, const float* __restrict__ qn,
        const u64* __restrict__ cand, const RowCtl* __restrict__ ctl,
        float* __restrict__ out, int Bn, int Vn){
  __shared__ u64 s_red[2][4];
  __shared__ u32 s_mk;
  __shared__ float s_fill[16];
  __shared__ Top5 s_wt5[NT4/64];
  __shared__ double s_wr[NT4/64];
  __shared__ int s_wri[NT4/64];
  __shared__ int s_wg[NT4/64];

  const int b = blockIdx.x, tid = threadIdx.x, lane = tid&63, w = tid>>6;
  const u32 n0raw = ctl[b].cnt0;
  if (n0raw == 0 || n0raw > CAP) return;      // handled by k5 row-fallback
  const int n0 = (int)n0raw;
  const float tr = temp[b]; const float tEff = (tr<1e-5f)?1.0f:tr;
  const float* Lr = L + (size_t)b*Vn;
  const float* Qr = qn + (size_t)b*Vn;
  const u64* Cr = cand + (size_t)b*CAP;
  const u32 kbMinKey = ctl[b].kb << BSH;

  // ---- load candidates into registers (stride layout, coalesced) ----
  if (tid==0) s_mk = 0;
  if (tid<16) s_fill[tid] = (tid<Vn) ? Lr[tid] : 0.f;
  __syncthreads();
  u32 k_[EPT], ix_[EPT];
  u32 valid = 0;
  u32 mk = 0;
  #pragma unroll
  for (int e=0;e<EPT;e++){
    int p = tid + e*NT4;
    if (p < n0){
      u64 v = Cr[p];
      k_[e] = (u32)(v>>32); ix_[e] = (u32)v;
      valid |= 1u<<e;
      mk = max(mk, k_[e]);
    } else { k_[e]=0u; ix_[e]=0u; }
  }
  for (int off=32; off; off>>=1){ u32 o=__shfl_xor(mk,off,64); mk=max(mk,o); }
  if (lane==0) atomicMax(&s_mk, mk);
  __syncthreads();
  const u32 mKey = s_mk;
  const float m = key_to_float(mKey);
  int buf = 0;

  // ---- descent A: exact k-th largest key (count weights) ----
  int kk = top_k[b]; if (kk<1) kk=1; if (kk>Vn) kk=Vn; if (kk>n0) kk=n0;
  u32 rA = (u32)(n0 - kk);                    // ascending 0-based rank
  const u32 xA = kbMinKey ^ mKey;
  const int sbA = xA ? (31 - __clz(xA)) : -1;
  u32 pfx = (sbA==31) ? 0u : (mKey & ((sbA>=0) ? ~((1u<<(sbA+1))-1u) : 0xFFFFFFFFu));
  u32 aA = valid;
  for (int bit=sbA; bit>=0; --bit){
    u32 c0 = 0;
    #pragma unroll
    for (int e=0;e<EPT;e++)
      c0 += ((aA>>e)&1u) & (((k_[e]>>bit)&1u)^1u);
    for (int off=32; off; off>>=1) c0 += __shfl_xor(c0, off, 64);
    if (lane==0) s_red[buf][w] = (u64)c0;
    __syncthreads();
    u32 C0 = (u32)(s_red[buf][0]+s_red[buf][1]+s_red[buf][2]+s_red[buf][3]);
    u32 chosen;
    if (rA < C0) chosen = 0u;
    else { rA -= C0; chosen = 1u; pfx |= (1u<<bit); }
    u32 na = 0;
    #pragma unroll
    for (int e=0;e<EPT;e++)
      na |= (((aA>>e)&1u) & ((((k_[e]>>bit)&1u)==chosen)?1u:0u)) << e;
    aA = na;
    buf ^= 1;
  }
  const u32 thrKey = pfx;                     // exact k-th largest key

  // ---- survivor masses + total T ----
  u64 ms_[EPT];
  u32 aB = 0;
  u64 locT = 0;
  #pragma unroll
  for (int e=0;e<EPT;e++){
    bool sv = ((valid>>e)&1u) && (k_[e] >= thrKey);
    ms_[e] = sv ? quantMass(key_to_float(k_[e]), m) : 0ull;
    if (sv) aB |= 1u<<e;
    locT += ms_[e];
  }
  for (int off=32; off; off>>=1) locT += __shfl_xor(locT, off, 64);
  if (lane==0) s_red[buf][w] = locT;
  __syncthreads();
  const u64 T = s_red[buf][0]+s_red[buf][1]+s_red[buf][2]+s_red[buf][3];
  buf ^= 1;
  const float cf = 1.0f - top_p[b];           // ref: f32 (1.0 - top_p)
  u64 Q = (u64)((double)cf * (double)T);
  if (Q >= T) Q = T - 1;                      // ref: p_mask[:, -1] = False
  const u64 budget = Q;

  // ---- descent B: top-p boundary key (mass weights) ----
  const u32 xB = thrKey ^ mKey;
  const int sbB = xB ? (31 - __clz(xB)) : -1;
  u32 pfx2 = (sbB==31) ? 0u : (mKey & ((sbB>=0) ? ~((1u<<(sbB+1))-1u) : 0xFFFFFFFFu));
  for (int bit=sbB; bit>=0; --bit){
    u64 S0 = 0;
    #pragma unroll
    for (int e=0;e<EPT;e++)
      if (((aB>>e)&1u) && !((k_[e]>>bit)&1u)) S0 += ms_[e];
    for (int off=32; off; off>>=1) S0 += __shfl_xor(S0, off, 64);
    if (lane==0) s_red[buf][w] = S0;
    __syncthreads();
    u64 St = s_red[buf][0]+s_red[buf][1]+s_red[buf][2]+s_red[buf][3];
    u32 chosen;
    if (Q < St) chosen = 0u;
    else { Q -= St; chosen = 1u; pfx2 |= (1u<<bit); }
    u32 na = 0;
    #pragma unroll
    for (int e=0;e<EPT;e++)
      na |= (((aB>>e)&1u) & ((((k_[e]>>bit)&1u)==chosen)?1u:0u)) << e;
    aB = na;
    buf ^= 1;
  }
  const u32 vKey = pfx2;                      // boundary key (always has mass > 0)
  const u64 qstar = quantMass(key_to_float(vKey), m);
  const u64 tmask = qstar ? (Q / qstar) : 0ull;   // # masked within equal-key group
  const u64 S2 = T - (budget - Q) - tmask*qstar;  // surviving mass (exact integer)

  // ---- descent C: tie-break index (tmask-th smallest idx in equal-key group) ----
  int idxStar = -1;
  if (tmask > 0){
    u32 r2 = (u32)(tmask - 1);
    u32 aC = 0;
    #pragma unroll
    for (int e=0;e<EPT;e++)
      if (((valid>>e)&1u) && k_[e]==vKey) aC |= 1u<<e;
    const int sbC = 31 - __clz((u32)(Vn-1));
    u32 pfx3 = 0;
    for (int bit=sbC; bit>=0; --bit){
      u32 c0 = 0;
      #pragma unroll
      for (int e=0;e<EPT;e++)
        c0 += ((aC>>e)&1u) & (((ix_[e]>>bit)&1u)^1u);
      for (int off=32; off; off>>=1) c0 += __shfl_xor(c0, off, 64);
      if (lane==0) s_red[buf][w] = (u64)c0;
      __syncthreads();
      u32 C0 = (u32)(s_red[buf][0]+s_red[buf][1]+s_red[buf][2]+s_red[buf][3]);
      u32 chosen;
      if (r2 < C0) chosen = 0u;
      else { r2 -= C0; chosen = 1u; pfx3 |= (1u<<bit); }
      u32 na = 0;
      #pragma unroll
      for (int e=0;e<EPT;e++)
        na |= (((aC>>e)&1u) & ((((ix_[e]>>bit)&1u)==chosen)?1u:0u)) << e;
      aC = na;
      buf ^= 1;
    }
    idxStar = (int)pfx3;
  }

  // ---- final: survivor flags, prefetched q-gather, Gumbel/greedy/top-5 ----
  u32 sv = 0;
  float qv[EPT];
  #pragma unroll
  for (int e=0;e<EPT;e++){
    bool s = ((valid>>e)&1u) &&
             ((k_[e] > vKey) || (k_[e] == vKey && (int)ix_[e] > idxStar));
    if (s) sv |= 1u<<e;
    qv[e] = s ? Qr[ix_[e]] : 1.0f;            // batched independent gathers
  }
  Top5 t5; t5_init(t5);
  double br = -1.0; int bri = 0x7FFFFFFF; int gmin = 0x7FFFFFFF;
  #pragma unroll
  for (int e=0;e<EPT;e++){
    if ((sv>>e)&1u){
      float l = key_to_float(k_[e]); int idx = (int)ix_[e];
      float u = expf(l - m);
      float ee = -logf(qv[e]);
      double ratio = (double)u / (double)ee;
      if (ratio > br || (ratio == br && idx < bri)){ br = ratio; bri = idx; }
      if (k_[e] == mKey && idx < gmin) gmin = idx;
      t5_insert(t5, l, idx);
    }
  }
  for (int off=1; off<64; off<<=1){
    Top5 o;
    for (int j=0;j<TOPN;j++){ o.v[j]=__shfl_xor(t5.v[j],off,64); o.ix[j]=__shfl_xor(t5.ix[j],off,64); }
    for (int j=0;j<TOPN;j++) t5_insert(t5, o.v[j], o.ix[j]);
    double orr = __shfl_xor(br, off, 64); int ori = __shfl_xor(bri, off, 64);
    if (orr > br || (orr == br && ori < bri)){ br = orr; bri = ori; }
    int og = __shfl_xor(gmin, off, 64); if (og < gmin) gmin = og;
  }
  if (lane==0){ s_wt5[w]=t5; s_wr[w]=br; s_wri[w]=bri; s_wg[w]=gmin; }
  __syncthreads();
  if (tid==0){
    Top5 f = s_wt5[0];
    double fr = s_wr[0]; int fri = s_wri[0]; int fg = s_wg[0];
    for (int wi=1; wi<NT4/64; wi++){
      for (int j=0;j<TOPN;j++) t5_insert(f, s_wt5[wi].v[j], s_wt5[wi].ix[j]);
      if (s_wr[wi] > fr || (s_wr[wi]==fr && s_wri[wi]<fri)){ fr=s_wr[wi]; fri=s_wri[wi]; }
      if (s_wg[wi] < fg) fg = s_wg[wi];
    }
    // -inf fill: 5 smallest non-surviving vocab indices live in [0,16) whenever they matter
    int filled = 0;
    for (int i=0; i<16 && i<Vn && filled<TOPN; i++){
      u32 k2 = key_of(s_fill[i]/tEff);
      bool surv2 = (k2 > vKey) || (k2 == vKey && i > idxStar);
      if (!surv2){ t5_insert(f, -INFINITY, i); filled++; }
    }
    double lS = log((double)S2 / SCALE_D);
    int sampled = (tr < 1e-5f) ? fg : fri;
    out[b] = (float)sampled;
    for (int j=0;j<TOPN;j++){
      float lv = f.v[j];
      float lp = (lv == -INFINITY) ? NEG_BIG : (float)((double)lv - (double)m - lS);
      out[Bn + b*TOPN + j] = lp;
      out[Bn + Bn*TOPN + b*TOPN + j] = (float)f.ix[j];
    }
  }
}

// ======================= per-row full fallback (round-2 algorithm, verified) =======================

__device__ void find_cross(const u64* arr, int n, u64 target, int* s_fh, u64* s_fb){
  const int tid = threadIdx.x;
  const int chunk = (n + NT - 1) / NT;
  const int base = tid * chunk;
  for (int j=0;j<chunk;j++){
    int i = base + j;
    if (i < n && arr[i] <= target && target < arr[i+1]){ *s_fh = i; *s_fb = arr[i]; }
  }
  __syncthreads();
}

__device__ void fallback_row(int b, const float* logits, const float* temperature,
                             const int* top_k, const float* top_p, const float* qnoise,
                             float* out, int Bn, int Vn){
  __shared__ u64 s_hist[4097];
  __shared__ u64 s_wsum[NW];
  __shared__ int s_fh;
  __shared__ u64 s_fb;
  __shared__ float s_fm[NW];
  __shared__ float s_m;
  __shared__ int s_lastMax;
  __shared__ int s_eqcnt;
  __shared__ int s_eqlist[1024];
  __shared__ int s_sel;
  __shared__ Top5 s_wt5[NW];
  __shared__ double s_wr[NW];
  __shared__ int s_wri[NW];
  __shared__ int s_wg[NW];
  __shared__ u64 s_ws2[NW];

  const int tid = threadIdx.x, lane = tid & 63, w = tid >> 6;
  const float* L  = logits + (size_t)b * Vn;
  const float* Qr = qnoise + (size_t)b * Vn;
  const float tRaw = temperature[b];
  const float tEff = (tRaw < 1e-5f) ? 1.0f : tRaw;

  for (int i=tid;i<4097;i+=NT) s_hist[i] = 0;
  if (tid==0){ s_lastMax = -1; s_eqcnt = 0; }
  __syncthreads();
  float lm = -INFINITY;
  for (int i=tid;i<Vn;i+=NT){
    float l = L[i] / tEff;
    u32 k = key_of(l);
    atomicAdd(&s_hist[k>>20], 1ull);
    lm = fmaxf(lm, l);
  }
  for (int off=32; off; off>>=1) lm = fmaxf(lm, __shfl_xor(lm, off, 64));
  if (lane==0) s_fm[w] = lm;
  scan_excl(s_hist, 4096, s_wsum);
  if (tid==0){ float mm=-INFINITY; for (int i=0;i<NW;i++) mm=fmaxf(mm,s_fm[i]); s_m=mm; }
  __syncthreads();
  const float m = s_m;

  int kk = top_k[b]; if (kk < 1) kk = 1; if (kk > Vn) kk = Vn;
  u64 r = (u64)(Vn - kk);
  find_cross(s_hist, 4096, r, &s_fh, &s_fb);
  const int kb0 = s_fh; r -= s_fb;
  __syncthreads();

  for (int i=tid;i<4097;i+=NT) s_hist[i]=0;
  __syncthreads();
  for (int i=tid;i<Vn;i+=NT){
    float l = L[i]/tEff; u32 k = key_of(l);
    if ((int)(k>>20) == kb0) atomicAdd(&s_hist[(k>>8)&0xFFFu], 1ull);
  }
  scan_excl(s_hist, 4096, s_wsum);
  find_cross(s_hist, 4096, r, &s_fh, &s_fb);
  const int kb1 = s_fh; r -= s_fb;
  __syncthreads();

  const u32 ktop24 = ((u32)kb0<<12) | (u32)kb1;
  for (int i=tid;i<4097;i+=NT) s_hist[i]=0;
  __syncthreads();
  for (int i=tid;i<Vn;i+=NT){
    float l = L[i]/tEff; u32 k = key_of(l);
    if ((k>>8) == ktop24) atomicAdd(&s_hist[k & 0xFFu], 1ull);
  }
  scan_excl(s_hist, 256, s_wsum);
  find_cross(s_hist, 256, r, &s_fh, &s_fb);
  const u32 thrKey = (ktop24<<8) | (u32)s_fh;
  const float thr = key_to_float(thrKey);
  __syncthreads();

  for (int i=tid;i<4097;i+=NT) s_hist[i]=0;
  __syncthreads();
  for (int i=tid;i<Vn;i+=NT){
    float l = L[i]/tEff;
    if (l >= thr){
      u32 k = key_of(l);
      double sd = exp((double)l - (double)m);
      u64 qv = (u64)(sd * SCALE_D + 0.5);
      atomicAdd(&s_hist[k>>20], qv);
      if (l == m) atomicMax(&s_lastMax, i);
    }
  }
  scan_excl(s_hist, 4096, s_wsum);
  const u64 T = s_hist[4096];
  const float cf = 1.0f - top_p[b];
  const double qtd = (double)cf * (double)T;
  u64 Qfix = (qtd >= (double)T) ? T : (u64)qtd;
  const bool allmask = (Qfix >= T);

  u32 vKey = 0xFFFFFFFFu;
  int idxStar = 0x7FFFFFFF;

  if (!allmask){
    find_cross(s_hist, 4096, Qfix, &s_fh, &s_fb);
    const int g0 = s_fh;
    u64 Qrem = Qfix - s_fb;
    __syncthreads();

    for (int i=tid;i<4097;i+=NT) s_hist[i]=0;
    __syncthreads();
    for (int i=tid;i<Vn;i+=NT){
      float l = L[i]/tEff;
      if (l >= thr){
        u32 k = key_of(l);
        if ((int)(k>>20) == g0){
          double sd = exp((double)l - (double)m);
          atomicAdd(&s_hist[(k>>8)&0xFFFu], (u64)(sd*SCALE_D+0.5));
        }
      }
    }
    scan_excl(s_hist, 4096, s_wsum);
    find_cross(s_hist, 4096, Qrem, &s_fh, &s_fb);
    const int g1 = s_fh; Qrem -= s_fb;
    __syncthreads();

    const u32 ptop24 = ((u32)g0<<12)|(u32)g1;
    for (int i=tid;i<4097;i+=NT) s_hist[i]=0;
    __syncthreads();
    for (int i=tid;i<Vn;i+=NT){
      float l = L[i]/tEff;
      if (l >= thr){
        u32 k = key_of(l);
        if ((k>>8) == ptop24){
          double sd = exp((double)l - (double)m);
          atomicAdd(&s_hist[k & 0xFFu], (u64)(sd*SCALE_D+0.5));
        }
      }
    }
    scan_excl(s_hist, 256, s_wsum);
    find_cross(s_hist, 256, Qrem, &s_fh, &s_fb);
    const int g2 = s_fh;
    const u64 base2 = s_fb;
    const u64 nextPref = s_hist[g2+1];
    Qrem -= base2;
    vKey = (ptop24<<8) | (u32)g2;
    const float vStar = key_to_float(vKey);
    const double sv = exp((double)vStar - (double)m);
    const u64 qstar = (u64)(sv*SCALE_D+0.5);
    u64 nstar = (qstar > 0) ? (nextPref - base2) / qstar : 1ull;
    if (nstar < 1) nstar = 1;
    u64 tmask = (qstar > 0) ? (Qrem / qstar) : 0ull;
    if (tmask >= nstar) tmask = nstar - 1;
    idxStar = -1;
    __syncthreads();
    if (tmask >= 1){
      for (int i=tid;i<Vn;i+=NT){
        float l = L[i]/tEff;
        if (key_of(l) == vKey){
          int p = atomicAdd(&s_eqcnt, 1);
          if (p < 1024) s_eqlist[p] = i;
        }
      }
      __syncthreads();
      if (tid == 0){
        int n_ = s_eqcnt; if (n_ > 1024) n_ = 1024;
        for (int a=1;a<n_;a++){
          int key0 = s_eqlist[a]; int c2=a-1;
          while (c2>=0 && s_eqlist[c2]>key0){ s_eqlist[c2+1]=s_eqlist[c2]; c2--; }
          s_eqlist[c2+1]=key0;
        }
        int ti = (int)tmask - 1;
        if (ti >= n_) ti = n_-1;
        s_sel = s_eqlist[ti];
      }
      __syncthreads();
      idxStar = s_sel;
    }
  }

  const int lastMax = s_lastMax;
  Top5 t5; t5_init(t5);
  u64 s2 = 0;
  double br = -1.0; int bri = 0x7FFFFFFF;
  int gmin = 0x7FFFFFFF;
  for (int i=tid;i<Vn;i+=NT){
    float l = L[i]/tEff;
    u32 k = key_of(l);
    bool surv = (l >= thr) &&
                ((k > vKey) || (k == vKey && i > idxStar) || (i == lastMax));
    float val;
    if (surv){
      double sd = exp((double)l - (double)m);
      s2 += (u64)(sd*SCALE_D+0.5);
      float u = expf(l - m);
      float e = -logf(Qr[i]);
      double ratio = (double)u / (double)e;
      if (ratio > br || (ratio == br && i < bri)){ br = ratio; bri = i; }
      if (l == m && i < gmin) gmin = i;
      val = l;
    } else {
      val = -INFINITY;
    }
    t5_insert(t5, val, i);
  }
  for (int off=1; off<64; off<<=1){
    Top5 o;
    for (int j=0;j<TOPN;j++){ o.v[j]=__shfl_xor(t5.v[j],off,64); o.ix[j]=__shfl_xor(t5.ix[j],off,64); }
    for (int j=0;j<TOPN;j++) t5_insert(t5, o.v[j], o.ix[j]);
    double orr = __shfl_xor(br, off, 64);
    int ori = __shfl_xor(bri, off, 64);
    if (orr > br || (orr == br && ori < bri)){ br = orr; bri = ori; }
    int og = __shfl_xor(gmin, off, 64); if (og < gmin) gmin = og;
    s2 += __shfl_xor(s2, off, 64);
  }
  if (lane == 0){
    s_wt5[w] = t5; s_wr[w]=br; s_wri[w]=bri; s_wg[w]=gmin; s_ws2[w]=s2;
  }
  __syncthreads();
  if (tid == 0){
    Top5 f = s_wt5[0];
    double fr = s_wr[0]; int fri = s_wri[0]; int fg = s_wg[0];
    u64 fs2 = s_ws2[0];
    for (int wi=1; wi<NW; wi++){
      for (int j=0;j<TOPN;j++) t5_insert(f, s_wt5[wi].v[j], s_wt5[wi].ix[j]);
      if (s_wr[wi] > fr || (s_wr[wi]==fr && s_wri[wi]<fri)){ fr=s_wr[wi]; fri=s_wri[wi]; }
      if (s_wg[wi] < fg) fg = s_wg[wi];
      fs2 += s_ws2[wi];
    }
    double S2d = (double)fs2 / SCALE_D;
    double lS = log(S2d);
    int sampled = (tRaw < 1e-5f) ? fg : fri;
    out[b] = (float)sampled;
    for (int j=0;j<TOPN;j++){
      float lv = f.v[j];
      float lp = (lv == -INFINITY) ? NEG_BIG : (float)((double)lv - (double)m - lS);
      out[Bn + b*TOPN + j] = lp;
      out[Bn + Bn*TOPN + b*TOPN + j] = (float)f.ix[j];
    }
  }
}

__global__ __launch_bounds__(NT) void k5_rowfb(const float* __restrict__ logits,
        const float* __restrict__ temperature, const int* __restrict__ top_k,
        const float* __restrict__ top_p, const float* __restrict__ qnoise,
        const RowCtl* __restrict__ ctl, float* __restrict__ out, int Bn, int Vn){
  const int b = blockIdx.x;
  const u32 c = ctl[b].cnt0;
  if (c > 0 && c <= CAP) return;   // handled by k4
  fallback_row(b, logits, temperature, top_k, top_p, qnoise, out, Bn, Vn);
}

extern "C" __global__ void __launch_bounds__(NT)
sampler_fallback(const float* __restrict__ logits, const float* __restrict__ temperature,
                 const int* __restrict__ top_k, const float* __restrict__ top_p,
                 const float* __restrict__ qnoise, float* __restrict__ out, int Bn, int Vn){
  fallback_row(blockIdx.x, logits, temperature, top_k, top_p, qnoise, out, Bn, Vn);
}

// ======================= launch =======================

extern "C" void kernel_launch(void* const* d_in, const int* in_sizes, int n_in,
                              void* d_out, int out_size, void* d_ws, size_t ws_size,
                              hipStream_t stream)
{
  const float* logits      = (const float*)d_in[0];
  const float* temperature = (const float*)d_in[1];
  const int*   top_k       = (const int*)d_in[2];
  const float* top_p       = (const float*)d_in[3];
  const float* q           = (const float*)d_in[4];
  const int Bn = in_sizes[1];
  const int Vn = in_sizes[0] / Bn;

  const size_t offCand = (size_t)Bn * NB * 4;                 // hist u32
  const size_t offCtl  = offCand + (size_t)Bn * CAP * 8;      // cand u64
  const size_t total   = offCtl + (size_t)Bn * sizeof(RowCtl);

  if (ws_size < total){
    sampler_fallback<<<dim3(Bn), dim3(NT), 0, stream>>>(
        logits, temperature, top_k, top_p, q, (float*)d_out, Bn, Vn);
    return;
  }

  char* wsb = (char*)d_ws;
  u32*    hist = (u32*)wsb;
  u64*    cand = (u64*)(wsb + offCand);
  RowCtl* ctl  = (RowCtl*)(wsb + offCtl);

  k0_zero   <<<dim3(512),     dim3(256), 0, stream>>>(hist, (u32*)ctl, Bn);
  k1_hist   <<<dim3(SL, Bn),  dim3(NT1), 0, stream>>>(logits, temperature, hist, Bn, Vn);
  k2_kb     <<<dim3(Bn),      dim3(NT),  0, stream>>>(top_k, hist, ctl, Bn, Vn);
  k3_collect<<<dim3(SL, Bn),  dim3(NT1), 0, stream>>>(logits, temperature, cand, ctl, Bn, Vn);
  k4_solve  <<<dim3(Bn),      dim3(NT4), 0, stream>>>(logits, temperature, top_k, top_p, q,
                                                      cand, ctl, (float*)d_out, Bn, Vn);
  k5_rowfb  <<<dim3(Bn),      dim3(NT),  0, stream>>>(logits, temperature, top_k, top_p, q,
                                                      ctl, (float*)d_out, Bn, Vn);
}